// Round 7
// baseline (232.464 us; speedup 1.0000x reference)
//
#include <hip/hip_runtime.h>
#include <stdint.h>

#define M_ 3
#define B_ 8
#define N_ 512
#define C_ 512
#define H_ 8
#define HD_ 64

typedef __bf16 bf16x8 __attribute__((ext_vector_type(8)));
typedef __bf16 bf16x2 __attribute__((ext_vector_type(2)));
typedef float f32x4 __attribute__((ext_vector_type(4)));
typedef float f32x16 __attribute__((ext_vector_type(16)));
typedef unsigned int u32x4 __attribute__((ext_vector_type(4)));

#if __has_builtin(__builtin_amdgcn_exp2f)
#define EXP2(x) __builtin_amdgcn_exp2f(x)
#else
#define EXP2(x) __expf((x)*0.69314718056f)
#endif

// K is pre-scaled by hd^-0.5 * log2(e) in the K-projection epilogue,
// so attention probabilities are exp2(S) directly.
#define K_PRESCALE 0.18033688f

static __device__ __forceinline__ unsigned short f2bf(float f) {
  unsigned int u = __float_as_uint(f);
  unsigned int r = (u + 0x7FFFu + ((u >> 16) & 1u)) >> 16;
  return (unsigned short)r;
}
static __device__ __forceinline__ float bf2f(unsigned short s) {
  return __uint_as_float(((unsigned int)s) << 16);
}

static __device__ __forceinline__ void gll16(const void* g, void* l) {
  __builtin_amdgcn_global_load_lds(
      (const __attribute__((address_space(1))) unsigned int*)g,
      (__attribute__((address_space(3))) unsigned int*)l, 16, 0, 0);
}

// ---------------- kernel 1: x (f32) -> bf16 ----------------
__global__ void convert_x_kernel(const float* __restrict__ x,
                                 unsigned short* __restrict__ xb, int n4) {
  int i = blockIdx.x * 256 + threadIdx.x;
  if (i < n4) {
    float4 v = ((const float4*)x)[i];
    ushort4 o;
    o.x = f2bf(v.x); o.y = f2bf(v.y); o.z = f2bf(v.z); o.w = f2bf(v.w);
    ((ushort4*)xb)[i] = o;
  }
}

// ---------------- kernel 2: W [c][d] f32 -> W^T [d][c] bf16 ----------------
__global__ void transpose_w_kernel(const float* __restrict__ Wq, const float* __restrict__ Wk,
                                   const float* __restrict__ Wv, const float* __restrict__ Wp,
                                   unsigned short* __restrict__ Wqt, unsigned short* __restrict__ Wkt,
                                   unsigned short* __restrict__ Wvt, unsigned short* __restrict__ Wpt) {
  int z = blockIdx.z;
  const float* src; unsigned short* dst;
  if (z < 3)      { src = Wq + z * 262144;      dst = Wqt + z * 262144; }
  else if (z < 6) { src = Wk + (z - 3) * 262144; dst = Wkt + (z - 3) * 262144; }
  else if (z < 9) { src = Wv + (z - 6) * 262144; dst = Wvt + (z - 6) * 262144; }
  else            { src = Wp;                    dst = Wpt; }
  __shared__ unsigned short t[64][68];
  int r0 = blockIdx.x * 64, c0 = blockIdx.y * 64;
  int tr = threadIdx.x >> 4, tc = (threadIdx.x & 15) * 4;
#pragma unroll
  for (int it = 0; it < 4; ++it) {
    int r = tr + it * 16;
    float4 v = *(const float4*)&src[(size_t)(r0 + r) * 512 + c0 + tc];
    t[tc + 0][r] = f2bf(v.x); t[tc + 1][r] = f2bf(v.y);
    t[tc + 2][r] = f2bf(v.z); t[tc + 3][r] = f2bf(v.w);
  }
  __syncthreads();
#pragma unroll
  for (int it = 0; it < 4; ++it) {
    int d = tr + it * 16;
    ushort4 o;
    o.x = t[d][tc + 0]; o.y = t[d][tc + 1]; o.z = t[d][tc + 2]; o.w = t[d][tc + 3];
    *(ushort4*)&dst[(size_t)(c0 + d) * 512 + r0 + tc] = o;
  }
}

// ---------------- kernel 3/6: 128x128 bf16 MFMA GEMM ----------------
template <int MODE>
__launch_bounds__(256, 2)
__global__ void gemm128_kernel(const unsigned short* __restrict__ Aall,
                               const unsigned short* __restrict__ Bt0,
                               const unsigned short* __restrict__ Bt1,
                               const unsigned short* __restrict__ Bt2,
                               const float* __restrict__ bias0,
                               const float* __restrict__ bias1,
                               const float* __restrict__ bias2,
                               unsigned short* __restrict__ outQ,
                               unsigned short* __restrict__ outK,
                               unsigned short* __restrict__ outVt,
                               float* __restrict__ outF) {
  const int tid = threadIdx.x;
  const int wv = tid >> 6, l = tid & 63;
  const int wr = wv >> 1, wc = wv & 1;
  const int bm = blockIdx.x, bn = blockIdx.y;
  int m = 0, p = 0;
  const unsigned short* A; const unsigned short* Bt; const float* bias;
  if (MODE == 0) {
    int z = blockIdx.z; m = z / 3; p = z % 3;
    A = Aall + (size_t)m * (B_ * N_ * C_);
    Bt = (p == 0 ? Bt0 : p == 1 ? Bt1 : Bt2) + (size_t)m * (C_ * C_);
    bias = (p == 0 ? bias0 : p == 1 ? bias1 : bias2) + m * C_;
  } else {
    A = Aall; Bt = Bt0; bias = bias0;
  }
  __shared__ __align__(16) unsigned short lA[2][128 * 64];
  __shared__ __align__(16) unsigned short lB[2][128 * 64];
  f32x4 acc[4][4] = {};

  auto stage = [&](int buf, int kt) {
    int k0 = kt * 64;
#pragma unroll
    for (int it = 0; it < 4; ++it) {
      int f = (it * 256 + tid) * 16;
      int r = f >> 7, o = f & 127;
      int so = o ^ ((r & 7) << 4);
      gll16((const char*)A + ((size_t)(bm * 128 + r) * 512 + k0) * 2 + so,
            (char*)&lA[buf][0] + (it * 256 + wv * 64) * 16);
      gll16((const char*)Bt + ((size_t)(bn * 128 + r) * 512 + k0) * 2 + so,
            (char*)&lB[buf][0] + (it * 256 + wv * 64) * 16);
    }
  };

  stage(0, 0);
  __syncthreads();
  int buf = 0;
  for (int kt = 0; kt < 8; ++kt) {
    if (kt < 7) stage(buf ^ 1, kt + 1);
    bf16x8 aF[4][2], bF[4][2];
#pragma unroll
    for (int rt = 0; rt < 4; ++rt)
#pragma unroll
      for (int kf = 0; kf < 2; ++kf) {
        int rowA = wr * 64 + rt * 16 + (l & 15);
        int rowB = wc * 64 + rt * 16 + (l & 15);
        int kb = kf * 64 + (l >> 4) * 16;
        aF[rt][kf] = *(const bf16x8*)((const char*)&lA[buf][0] + rowA * 128 + (kb ^ ((rowA & 7) << 4)));
        bF[rt][kf] = *(const bf16x8*)((const char*)&lB[buf][0] + rowB * 128 + (kb ^ ((rowB & 7) << 4)));
      }
#pragma unroll
    for (int kf = 0; kf < 2; ++kf)
#pragma unroll
      for (int rt = 0; rt < 4; ++rt)
#pragma unroll
        for (int ct = 0; ct < 4; ++ct)
          acc[rt][ct] = __builtin_amdgcn_mfma_f32_16x16x32_bf16(aF[rt][kf], bF[ct][kf], acc[rt][ct], 0, 0, 0);
    __syncthreads();
    buf ^= 1;
  }

  const float vscale = (MODE == 0 && p == 1) ? K_PRESCALE : 1.0f;
#pragma unroll
  for (int rt = 0; rt < 4; ++rt) {
    int rbase = bm * 128 + wr * 64 + rt * 16 + (l >> 4) * 4;
#pragma unroll
    for (int ct = 0; ct < 4; ++ct) {
      int col = bn * 128 + wc * 64 + ct * 16 + (l & 15);
      float bb = bias[col];
      if (MODE == 0) {
        int h = col >> 6, hd = col & 63;
        if (p < 2) {
          unsigned short* out = (p == 0 ? outQ : outK) + (size_t)m * (B_ * H_ * N_ * HD_);
#pragma unroll
          for (int jr = 0; jr < 4; ++jr) {
            int row = rbase + jr; int b = row >> 9, n = row & 511;
            out[(((size_t)(b * H_ + h) * N_ + n) * HD_) + hd] = f2bf((acc[rt][ct][jr] + bb) * vscale);
          }
        } else {
          unsigned short* out = outVt + (size_t)m * (B_ * H_ * HD_ * N_);
          int row = rbase; int b = row >> 9, n = row & 511;
          ushort4 o;
          o.x = f2bf(acc[rt][ct][0] + bb);
          o.y = f2bf(acc[rt][ct][1] + bb);
          o.z = f2bf(acc[rt][ct][2] + bb);
          o.w = f2bf(acc[rt][ct][3] + bb);
          *(ushort4*)&out[(((size_t)(b * H_ + h) * HD_ + hd) * N_) + n] = o;
        }
      } else {
#pragma unroll
        for (int jr = 0; jr < 4; ++jr) {
          int row = rbase + jr;
          outF[(size_t)row * C_ + col] = acc[rt][ct][jr] + bb;
        }
      }
    }
  }
}

// ---------------- kernel 4: pairwise attention v5 ----------------
// K A-frags loaded DIRECTLY from global (16B contiguous, L1/L2-hot, shared by
// 12 XCD-co-located blocks): kills K staging, K-side LDS bank conflicts, and
// the QK->barrier coupling. V stays in LDS (broadcast reuse). T5 setprio
// around MFMA clusters.
__launch_bounds__(256, 4)
__global__ void attn_kernel(const unsigned short* __restrict__ qg,
                            const unsigned short* __restrict__ kg,
                            const unsigned short* __restrict__ vg,
                            const float* __restrict__ mw,
                            unsigned short* __restrict__ att9) {
  const int tid = threadIdx.x;
  const int wv = tid >> 6, l = tid & 63;
  const int hi = l >> 5, lq = l & 31;
  const int xcd = blockIdx.x & 7, slot = blockIdx.x >> 3;
  const int bh = (xcd << 3) | (slot & 7);   // blocks sharing (b,h) co-locate per XCD
  const int r_ = slot >> 3;                 // 0..35
  const int qt = r_ & 3, ij = r_ >> 2;      // ij = i*3+j, 0..8
  const int i = ij / 3, j = ij % 3;
  const int b = bh >> 3, h = bh & 7;
  const int n0 = qt * 128;

  __shared__ __align__(16) unsigned short lV[2][64 * 64];

  // Q B-frags: lane holds Q[q = n0+wv*32+lq][d = ks*16 + hi*8 + 0..7]
  bf16x8 qB[4];
  {
    const unsigned short* qb = qg + (size_t)((i * B_ + b) * H_ + h) * N_ * HD_;
    int n = n0 + wv * 32 + lq;
#pragma unroll
    for (int ks = 0; ks < 4; ++ks)
      qB[ks] = *(const bf16x8*)&qb[(size_t)n * HD_ + ks * 16 + hi * 8];
  }
  bf16x8 onesB;
#pragma unroll
  for (int zz = 0; zz < 8; ++zz) onesB[zz] = (__bf16)1.0f;

  const char* kb = (const char*)(kg + (size_t)((j * B_ + b) * H_ + h) * N_ * HD_);
  const char* vb = (const char*)(vg + (size_t)((j * B_ + b) * H_ + h) * HD_ * N_);
  auto stageV = [&](int buf, int kt) {
#pragma unroll
    for (int it = 0; it < 2; ++it) {
      int f = (it * 256 + tid) * 16;
      int r = f >> 7, o = f & 127;
      int so = o ^ ((r & 7) << 4);
      gll16(vb + r * 1024 + kt * 128 + so, (char*)&lV[buf][0] + (it * 256 + wv * 64) * 16);
    }
  };
  stageV(0, 0);
  __syncthreads();

  f32x16 oacc[2] = {};
  f32x16 dacc = {};
  int buf = 0;
  for (int kt = 0; kt < 8; ++kt) {
    if (kt < 7) stageV(buf ^ 1, kt + 1);
#pragma unroll
    for (int kt2 = 0; kt2 < 2; ++kt2) {
      // K A-frags from global: row = kt*64+kt2*32+lq, bytes ks*32 + hi*16
      bf16x8 kA[4];
      {
        const char* krow = kb + (size_t)(kt * 64 + kt2 * 32 + lq) * 128 + hi * 16;
#pragma unroll
        for (int ks = 0; ks < 4; ++ks)
          kA[ks] = *(const bf16x8*)(krow + ks * 32);
      }
      // S^T tile: rows = 32 keys, cols = 32 q (swapped operands)
      f32x16 sT = {};
      __builtin_amdgcn_s_setprio(1);
#pragma unroll
      for (int ks = 0; ks < 4; ++ks)
        sT = __builtin_amdgcn_mfma_f32_32x32x16_bf16(kA[ks], qB[ks], sT, 0, 0, 0);
      __builtin_amdgcn_s_setprio(0);
      // P = exp2(S) (K pre-scaled); pack pairs via compiler cvt_pk
      unsigned int c[8];
#pragma unroll
      for (int w = 0; w < 8; ++w) {
        bf16x2 t2;
        t2[0] = (__bf16)EXP2(sT[2 * w]);
        t2[1] = (__bf16)EXP2(sT[2 * w + 1]);
        c[w] = __builtin_bit_cast(unsigned int, t2);
      }
      // PV + denominator per 16-key slice
      __builtin_amdgcn_s_setprio(1);
#pragma unroll
      for (int hs = 0; hs < 2; ++hs) {
        int ks = kt2 * 2 + hs;
        unsigned int s0 = hi ? c[4 * hs + 0] : c[4 * hs + 2];
        unsigned int s1 = hi ? c[4 * hs + 1] : c[4 * hs + 3];
        unsigned int r0 = (unsigned int)__shfl_xor((int)s0, 32, 64);
        unsigned int r1 = (unsigned int)__shfl_xor((int)s1, 32, 64);
        u32x4 pw;
        pw.x = hi ? r0 : c[4 * hs + 0];
        pw.y = hi ? r1 : c[4 * hs + 1];
        pw.z = hi ? c[4 * hs + 2] : r0;
        pw.w = hi ? c[4 * hs + 3] : r1;
        bf16x8 pA = __builtin_bit_cast(bf16x8, pw);
        dacc = __builtin_amdgcn_mfma_f32_32x32x16_bf16(pA, onesB, dacc, 0, 0, 0);
#pragma unroll
        for (int ht = 0; ht < 2; ++ht) {
          int row = ht * 32 + lq;
          int col = (ks * 32 + hi * 16) ^ ((row & 7) << 4);
          bf16x8 vB = *(const bf16x8*)((const char*)&lV[buf][0] + row * 128 + col);
          oacc[ht] = __builtin_amdgcn_mfma_f32_32x32x16_bf16(pA, vB, oacc[ht], 0, 0, 0);
        }
      }
      __builtin_amdgcn_s_setprio(0);
    }
    __syncthreads();
    buf ^= 1;
  }

  // finish: weight / denominator (lane-local: dacc has same C/D layout), write
  float w = mw[ij] * (1.0f / 3.0f);
  unsigned short* outp = att9 + (size_t)ij * (B_ * N_ * C_);
#pragma unroll
  for (int reg = 0; reg < 16; ++reg) {
    float t = w / dacc[reg];
    int n = n0 + wv * 32 + (reg & 3) + 8 * (reg >> 2) + 4 * hi;
#pragma unroll
    for (int ht = 0; ht < 2; ++ht) {
      int cc = h * 64 + ht * 32 + lq;
      outp[((size_t)b * N_ + n) * C_ + cc] = f2bf(oacc[ht][reg] * t);
    }
  }
}

// ---------------- kernel 5: sum 9 weighted partials -> fused bf16 ----------------
__global__ void sum9_kernel(const unsigned short* __restrict__ att9,
                            unsigned short* __restrict__ o, int n8) {
  int idx = blockIdx.x * 256 + threadIdx.x;
  if (idx >= n8) return;
  float acc[8] = {};
#pragma unroll
  for (int s = 0; s < 9; ++s) {
    uint4 v = ((const uint4*)(att9 + (size_t)s * (B_ * N_ * C_)))[idx];
    acc[0] += bf2f((unsigned short)(v.x & 0xffff));
    acc[1] += bf2f((unsigned short)(v.x >> 16));
    acc[2] += bf2f((unsigned short)(v.y & 0xffff));
    acc[3] += bf2f((unsigned short)(v.y >> 16));
    acc[4] += bf2f((unsigned short)(v.z & 0xffff));
    acc[5] += bf2f((unsigned short)(v.z >> 16));
    acc[6] += bf2f((unsigned short)(v.w & 0xffff));
    acc[7] += bf2f((unsigned short)(v.w >> 16));
  }
  uint4 r;
  r.x = (unsigned int)f2bf(acc[0]) | ((unsigned int)f2bf(acc[1]) << 16);
  r.y = (unsigned int)f2bf(acc[2]) | ((unsigned int)f2bf(acc[3]) << 16);
  r.z = (unsigned int)f2bf(acc[4]) | ((unsigned int)f2bf(acc[5]) << 16);
  r.w = (unsigned int)f2bf(acc[6]) | ((unsigned int)f2bf(acc[7]) << 16);
  ((uint4*)o)[idx] = r;
}

extern "C" void kernel_launch(void* const* d_in, const int* in_sizes, int n_in,
                              void* d_out, int out_size, void* d_ws, size_t ws_size,
                              hipStream_t stream) {
  const float* x  = (const float*)d_in[0];
  const float* Wq = (const float*)d_in[1];
  const float* bq = (const float*)d_in[2];
  const float* Wk = (const float*)d_in[3];
  const float* bk = (const float*)d_in[4];
  const float* Wv = (const float*)d_in[5];
  const float* bv = (const float*)d_in[6];
  const float* mw = (const float*)d_in[7];
  const float* Wp = (const float*)d_in[8];
  const float* bp = (const float*)d_in[9];
  float* out = (float*)d_out;

  char* ws = (char*)d_ws;
  size_t off = 0;
  auto alloc = [&](size_t elems) {
    unsigned short* pp = (unsigned short*)(ws + off);
    off += elems * 2; off = (off + 255) & ~(size_t)255;
    return pp;
  };
  unsigned short* xb   = alloc((size_t)M_ * B_ * N_ * C_);
  unsigned short* Wqt  = alloc((size_t)M_ * C_ * C_);
  unsigned short* Wkt  = alloc((size_t)M_ * C_ * C_);
  unsigned short* Wvt  = alloc((size_t)M_ * C_ * C_);
  unsigned short* Wpt  = alloc((size_t)C_ * C_);
  unsigned short* qb   = alloc((size_t)M_ * B_ * H_ * N_ * HD_);
  unsigned short* kb   = alloc((size_t)M_ * B_ * H_ * N_ * HD_);
  unsigned short* vtb  = alloc((size_t)M_ * B_ * H_ * HD_ * N_);
  unsigned short* att9 = alloc((size_t)9 * B_ * N_ * C_);
  unsigned short* fb   = alloc((size_t)B_ * N_ * C_);

  convert_x_kernel<<<6144, 256, 0, stream>>>(x, xb, (M_ * B_ * N_ * C_) / 4);
  transpose_w_kernel<<<dim3(8, 8, 10), 256, 0, stream>>>(Wq, Wk, Wv, Wp, Wqt, Wkt, Wvt, Wpt);
  gemm128_kernel<0><<<dim3(32, 4, 9), 256, 0, stream>>>(xb, Wqt, Wkt, Wvt, bq, bk, bv,
                                                        qb, kb, vtb, nullptr);
  attn_kernel<<<2304, 256, 0, stream>>>(qb, kb, vtb, mw, att9);
  sum9_kernel<<<1024, 256, 0, stream>>>(att9, fb, (B_ * N_ * C_) / 8);
  gemm128_kernel<1><<<dim3(32, 4, 1), 256, 0, stream>>>(fb, Wpt, nullptr, nullptr, bp, nullptr, nullptr,
                                                        nullptr, nullptr, nullptr, out);
}

// Round 8
// 202.191 us; speedup vs baseline: 1.1497x; 1.1497x over previous
//
#include <hip/hip_runtime.h>
#include <stdint.h>

#define M_ 3
#define B_ 8
#define N_ 512
#define C_ 512
#define H_ 8
#define HD_ 64

typedef __bf16 bf16x8 __attribute__((ext_vector_type(8)));
typedef __bf16 bf16x2 __attribute__((ext_vector_type(2)));
typedef float f32x4 __attribute__((ext_vector_type(4)));
typedef float f32x16 __attribute__((ext_vector_type(16)));
typedef unsigned int u32x4 __attribute__((ext_vector_type(4)));

#if __has_builtin(__builtin_amdgcn_exp2f)
#define EXP2(x) __builtin_amdgcn_exp2f(x)
#else
#define EXP2(x) __expf((x)*0.69314718056f)
#endif

// K is pre-scaled by hd^-0.5 * log2(e) in the K-projection epilogue,
// so attention probabilities are exp2(S) directly.
#define K_PRESCALE 0.18033688f

static __device__ __forceinline__ unsigned short f2bf(float f) {
  unsigned int u = __float_as_uint(f);
  unsigned int r = (u + 0x7FFFu + ((u >> 16) & 1u)) >> 16;
  return (unsigned short)r;
}
static __device__ __forceinline__ float bf2f(unsigned short s) {
  return __uint_as_float(((unsigned int)s) << 16);
}

static __device__ __forceinline__ void gll16(const void* g, void* l) {
  __builtin_amdgcn_global_load_lds(
      (const __attribute__((address_space(1))) unsigned int*)g,
      (__attribute__((address_space(3))) unsigned int*)l, 16, 0, 0);
}

// ---------------- kernel 1: x (f32) -> bf16 ----------------
__global__ void convert_x_kernel(const float* __restrict__ x,
                                 unsigned short* __restrict__ xb, int n4) {
  int i = blockIdx.x * 256 + threadIdx.x;
  if (i < n4) {
    float4 v = ((const float4*)x)[i];
    ushort4 o;
    o.x = f2bf(v.x); o.y = f2bf(v.y); o.z = f2bf(v.z); o.w = f2bf(v.w);
    ((ushort4*)xb)[i] = o;
  }
}

// ---------------- kernel 2: W [c][d] f32 -> W^T [d][c] bf16 ----------------
__global__ void transpose_w_kernel(const float* __restrict__ Wq, const float* __restrict__ Wk,
                                   const float* __restrict__ Wv, const float* __restrict__ Wp,
                                   unsigned short* __restrict__ Wqt, unsigned short* __restrict__ Wkt,
                                   unsigned short* __restrict__ Wvt, unsigned short* __restrict__ Wpt) {
  int z = blockIdx.z;
  const float* src; unsigned short* dst;
  if (z < 3)      { src = Wq + z * 262144;      dst = Wqt + z * 262144; }
  else if (z < 6) { src = Wk + (z - 3) * 262144; dst = Wkt + (z - 3) * 262144; }
  else if (z < 9) { src = Wv + (z - 6) * 262144; dst = Wvt + (z - 6) * 262144; }
  else            { src = Wp;                    dst = Wpt; }
  __shared__ unsigned short t[64][68];
  int r0 = blockIdx.x * 64, c0 = blockIdx.y * 64;
  int tr = threadIdx.x >> 4, tc = (threadIdx.x & 15) * 4;
#pragma unroll
  for (int it = 0; it < 4; ++it) {
    int r = tr + it * 16;
    float4 v = *(const float4*)&src[(size_t)(r0 + r) * 512 + c0 + tc];
    t[tc + 0][r] = f2bf(v.x); t[tc + 1][r] = f2bf(v.y);
    t[tc + 2][r] = f2bf(v.z); t[tc + 3][r] = f2bf(v.w);
  }
  __syncthreads();
#pragma unroll
  for (int it = 0; it < 4; ++it) {
    int d = tr + it * 16;
    ushort4 o;
    o.x = t[d][tc + 0]; o.y = t[d][tc + 1]; o.z = t[d][tc + 2]; o.w = t[d][tc + 3];
    *(ushort4*)&dst[(size_t)(c0 + d) * 512 + r0 + tc] = o;
  }
}

// ---------------- kernel 3/6: 128x128 bf16 MFMA GEMM ----------------
template <int MODE>
__launch_bounds__(256, 2)
__global__ void gemm128_kernel(const unsigned short* __restrict__ Aall,
                               const unsigned short* __restrict__ Bt0,
                               const unsigned short* __restrict__ Bt1,
                               const unsigned short* __restrict__ Bt2,
                               const float* __restrict__ bias0,
                               const float* __restrict__ bias1,
                               const float* __restrict__ bias2,
                               unsigned short* __restrict__ outQ,
                               unsigned short* __restrict__ outK,
                               unsigned short* __restrict__ outVt,
                               float* __restrict__ outF) {
  const int tid = threadIdx.x;
  const int wv = tid >> 6, l = tid & 63;
  const int wr = wv >> 1, wc = wv & 1;
  const int bm = blockIdx.x, bn = blockIdx.y;
  int m = 0, p = 0;
  const unsigned short* A; const unsigned short* Bt; const float* bias;
  if (MODE == 0) {
    int z = blockIdx.z; m = z / 3; p = z % 3;
    A = Aall + (size_t)m * (B_ * N_ * C_);
    Bt = (p == 0 ? Bt0 : p == 1 ? Bt1 : Bt2) + (size_t)m * (C_ * C_);
    bias = (p == 0 ? bias0 : p == 1 ? bias1 : bias2) + m * C_;
  } else {
    A = Aall; Bt = Bt0; bias = bias0;
  }
  __shared__ __align__(16) unsigned short lA[2][128 * 64];
  __shared__ __align__(16) unsigned short lB[2][128 * 64];
  f32x4 acc[4][4] = {};

  auto stage = [&](int buf, int kt) {
    int k0 = kt * 64;
#pragma unroll
    for (int it = 0; it < 4; ++it) {
      int f = (it * 256 + tid) * 16;
      int r = f >> 7, o = f & 127;
      int so = o ^ ((r & 7) << 4);
      gll16((const char*)A + ((size_t)(bm * 128 + r) * 512 + k0) * 2 + so,
            (char*)&lA[buf][0] + (it * 256 + wv * 64) * 16);
      gll16((const char*)Bt + ((size_t)(bn * 128 + r) * 512 + k0) * 2 + so,
            (char*)&lB[buf][0] + (it * 256 + wv * 64) * 16);
    }
  };

  stage(0, 0);
  __syncthreads();
  int buf = 0;
  for (int kt = 0; kt < 8; ++kt) {
    if (kt < 7) stage(buf ^ 1, kt + 1);
    bf16x8 aF[4][2], bF[4][2];
#pragma unroll
    for (int rt = 0; rt < 4; ++rt)
#pragma unroll
      for (int kf = 0; kf < 2; ++kf) {
        int rowA = wr * 64 + rt * 16 + (l & 15);
        int rowB = wc * 64 + rt * 16 + (l & 15);
        int kb = kf * 64 + (l >> 4) * 16;
        aF[rt][kf] = *(const bf16x8*)((const char*)&lA[buf][0] + rowA * 128 + (kb ^ ((rowA & 7) << 4)));
        bF[rt][kf] = *(const bf16x8*)((const char*)&lB[buf][0] + rowB * 128 + (kb ^ ((rowB & 7) << 4)));
      }
#pragma unroll
    for (int kf = 0; kf < 2; ++kf)
#pragma unroll
      for (int rt = 0; rt < 4; ++rt)
#pragma unroll
        for (int ct = 0; ct < 4; ++ct)
          acc[rt][ct] = __builtin_amdgcn_mfma_f32_16x16x32_bf16(aF[rt][kf], bF[ct][kf], acc[rt][ct], 0, 0, 0);
    __syncthreads();
    buf ^= 1;
  }

  const float vscale = (MODE == 0 && p == 1) ? K_PRESCALE : 1.0f;
#pragma unroll
  for (int rt = 0; rt < 4; ++rt) {
    int rbase = bm * 128 + wr * 64 + rt * 16 + (l >> 4) * 4;
#pragma unroll
    for (int ct = 0; ct < 4; ++ct) {
      int col = bn * 128 + wc * 64 + ct * 16 + (l & 15);
      float bb = bias[col];
      if (MODE == 0) {
        int h = col >> 6, hd = col & 63;
        if (p < 2) {
          unsigned short* out = (p == 0 ? outQ : outK) + (size_t)m * (B_ * H_ * N_ * HD_);
#pragma unroll
          for (int jr = 0; jr < 4; ++jr) {
            int row = rbase + jr; int b = row >> 9, n = row & 511;
            out[(((size_t)(b * H_ + h) * N_ + n) * HD_) + hd] = f2bf((acc[rt][ct][jr] + bb) * vscale);
          }
        } else {
          unsigned short* out = outVt + (size_t)m * (B_ * H_ * HD_ * N_);
          int row = rbase; int b = row >> 9, n = row & 511;
          ushort4 o;
          o.x = f2bf(acc[rt][ct][0] + bb);
          o.y = f2bf(acc[rt][ct][1] + bb);
          o.z = f2bf(acc[rt][ct][2] + bb);
          o.w = f2bf(acc[rt][ct][3] + bb);
          *(ushort4*)&out[(((size_t)(b * H_ + h) * HD_ + hd) * N_) + n] = o;
        }
      } else {
#pragma unroll
        for (int jr = 0; jr < 4; ++jr) {
          int row = rbase + jr;
          outF[(size_t)row * C_ + col] = acc[rt][ct][jr] + bb;
        }
      }
    }
  }
}

// ---------------- kernel 4: pairwise attention v6 ----------------
// v4 structure (K and V double-buffered in LDS) but staged in MFMA-FRAGMENT
// ORDER: LDS chunk (frag_id*64 + lane)*16 holds exactly that lane's 16B
// fragment (per-lane global source, m173). Fragment ds_read_b128 are fully
// linear -> zero bank conflicts, no XOR math in the inner loop.
__launch_bounds__(256, 4)
__global__ void attn_kernel(const unsigned short* __restrict__ qg,
                            const unsigned short* __restrict__ kg,
                            const unsigned short* __restrict__ vg,
                            const float* __restrict__ mw,
                            unsigned short* __restrict__ att9) {
  const int tid = threadIdx.x;
  const int wv = tid >> 6, l = tid & 63;
  const int hi = l >> 5, lq = l & 31;
  const int xcd = blockIdx.x & 7, slot = blockIdx.x >> 3;
  const int bh = (xcd << 3) | (slot & 7);   // blocks sharing (b,h) co-locate per XCD
  const int r_ = slot >> 3;                 // 0..35
  const int qt = r_ & 3, ij = r_ >> 2;      // ij = i*3+j, 0..8
  const int i = ij / 3, j = ij % 3;
  const int b = bh >> 3, h = bh & 7;
  const int n0 = qt * 128;

  __shared__ __align__(16) unsigned short lK[2][64 * 64];
  __shared__ __align__(16) unsigned short lV[2][64 * 64];

  // Q B-frags: lane holds Q[q = n0+wv*32+lq][d = ks*16 + hi*8 + 0..7]
  bf16x8 qB[4];
  {
    const unsigned short* qb = qg + (size_t)((i * B_ + b) * H_ + h) * N_ * HD_;
    int n = n0 + wv * 32 + lq;
#pragma unroll
    for (int ks = 0; ks < 4; ++ks)
      qB[ks] = *(const bf16x8*)&qb[(size_t)n * HD_ + ks * 16 + hi * 8];
  }
  bf16x8 onesB;
#pragma unroll
  for (int zz = 0; zz < 8; ++zz) onesB[zz] = (__bf16)1.0f;

  const char* kb = (const char*)(kg + (size_t)((j * B_ + b) * H_ + h) * N_ * HD_);
  const char* vb = (const char*)(vg + (size_t)((j * B_ + b) * H_ + h) * HD_ * N_);
  // Fragment-ordered staging. Chunk c = it*256+tid (512 chunks of 16B per tile):
  //  K: c = (kt2*4+ks)*64 + l  -> src K[key=kt*64+kt2*32+(l&31)][d-bytes ks*32+(l>>5)*16]
  //  V: c = (ksg*2+ht)*64 + l  -> src V[hd=ht*32+(l&31)][key-bytes kt*128+ksg*32+(l>>5)*16]
  auto stage = [&](int buf, int kt) {
#pragma unroll
    for (int it = 0; it < 2; ++it) {
      int c = it * 256 + tid;
      int fi = c >> 6, ll = c & 63;
      int lo = ll & 31, hh = ll >> 5;
      int kkt2 = fi >> 2, kks = fi & 3;
      gll16(kb + (size_t)(kt * 64 + kkt2 * 32 + lo) * 128 + kks * 32 + hh * 16,
            (char*)&lK[buf][0] + (it * 256 + wv * 64) * 16);
      int vks = fi >> 1, vht = fi & 1;
      gll16(vb + (size_t)(vht * 32 + lo) * 1024 + kt * 128 + vks * 32 + hh * 16,
            (char*)&lV[buf][0] + (it * 256 + wv * 64) * 16);
    }
  };
  stage(0, 0);
  __syncthreads();

  f32x16 oacc[2] = {};
  f32x16 dacc = {};
  int buf = 0;
  for (int kt = 0; kt < 8; ++kt) {
    if (kt < 7) stage(buf ^ 1, kt + 1);
#pragma unroll
    for (int kt2 = 0; kt2 < 2; ++kt2) {
      // S^T tile: rows = 32 keys, cols = 32 q (swapped operands)
      f32x16 sT = {};
      __builtin_amdgcn_s_setprio(1);
#pragma unroll
      for (int ks = 0; ks < 4; ++ks) {
        bf16x8 kA = *(const bf16x8*)((const char*)&lK[buf][0] + ((kt2 * 4 + ks) * 64 + l) * 16);
        sT = __builtin_amdgcn_mfma_f32_32x32x16_bf16(kA, qB[ks], sT, 0, 0, 0);
      }
      __builtin_amdgcn_s_setprio(0);
      // P = exp2(S) (K pre-scaled); pack pairs via compiler cvt_pk
      unsigned int c[8];
#pragma unroll
      for (int w = 0; w < 8; ++w) {
        bf16x2 t2;
        t2[0] = (__bf16)EXP2(sT[2 * w]);
        t2[1] = (__bf16)EXP2(sT[2 * w + 1]);
        c[w] = __builtin_bit_cast(unsigned int, t2);
      }
      // PV + denominator per 16-key slice
      __builtin_amdgcn_s_setprio(1);
#pragma unroll
      for (int hs = 0; hs < 2; ++hs) {
        int ksg = kt2 * 2 + hs;
        unsigned int s0 = hi ? c[4 * hs + 0] : c[4 * hs + 2];
        unsigned int s1 = hi ? c[4 * hs + 1] : c[4 * hs + 3];
        unsigned int r0 = (unsigned int)__shfl_xor((int)s0, 32, 64);
        unsigned int r1 = (unsigned int)__shfl_xor((int)s1, 32, 64);
        u32x4 pw;
        pw.x = hi ? r0 : c[4 * hs + 0];
        pw.y = hi ? r1 : c[4 * hs + 1];
        pw.z = hi ? c[4 * hs + 2] : r0;
        pw.w = hi ? c[4 * hs + 3] : r1;
        bf16x8 pA = __builtin_bit_cast(bf16x8, pw);
        dacc = __builtin_amdgcn_mfma_f32_32x32x16_bf16(pA, onesB, dacc, 0, 0, 0);
#pragma unroll
        for (int ht = 0; ht < 2; ++ht) {
          bf16x8 vB = *(const bf16x8*)((const char*)&lV[buf][0] + ((ksg * 2 + ht) * 64 + l) * 16);
          oacc[ht] = __builtin_amdgcn_mfma_f32_32x32x16_bf16(pA, vB, oacc[ht], 0, 0, 0);
        }
      }
      __builtin_amdgcn_s_setprio(0);
    }
    __syncthreads();
    buf ^= 1;
  }

  // finish: weight / denominator (lane-local: dacc has same C/D layout), write
  float w = mw[ij] * (1.0f / 3.0f);
  unsigned short* outp = att9 + (size_t)ij * (B_ * N_ * C_);
#pragma unroll
  for (int reg = 0; reg < 16; ++reg) {
    float t = w / dacc[reg];
    int n = n0 + wv * 32 + (reg & 3) + 8 * (reg >> 2) + 4 * hi;
#pragma unroll
    for (int ht = 0; ht < 2; ++ht) {
      int cc = h * 64 + ht * 32 + lq;
      outp[((size_t)b * N_ + n) * C_ + cc] = f2bf(oacc[ht][reg] * t);
    }
  }
}

// ---------------- kernel 5: sum 9 weighted partials -> fused bf16 ----------------
__global__ void sum9_kernel(const unsigned short* __restrict__ att9,
                            unsigned short* __restrict__ o, int n8) {
  int idx = blockIdx.x * 256 + threadIdx.x;
  if (idx >= n8) return;
  float acc[8] = {};
#pragma unroll
  for (int s = 0; s < 9; ++s) {
    uint4 v = ((const uint4*)(att9 + (size_t)s * (B_ * N_ * C_)))[idx];
    acc[0] += bf2f((unsigned short)(v.x & 0xffff));
    acc[1] += bf2f((unsigned short)(v.x >> 16));
    acc[2] += bf2f((unsigned short)(v.y & 0xffff));
    acc[3] += bf2f((unsigned short)(v.y >> 16));
    acc[4] += bf2f((unsigned short)(v.z & 0xffff));
    acc[5] += bf2f((unsigned short)(v.z >> 16));
    acc[6] += bf2f((unsigned short)(v.w & 0xffff));
    acc[7] += bf2f((unsigned short)(v.w >> 16));
  }
  uint4 r;
  r.x = (unsigned int)f2bf(acc[0]) | ((unsigned int)f2bf(acc[1]) << 16);
  r.y = (unsigned int)f2bf(acc[2]) | ((unsigned int)f2bf(acc[3]) << 16);
  r.z = (unsigned int)f2bf(acc[4]) | ((unsigned int)f2bf(acc[5]) << 16);
  r.w = (unsigned int)f2bf(acc[6]) | ((unsigned int)f2bf(acc[7]) << 16);
  ((uint4*)o)[idx] = r;
}

extern "C" void kernel_launch(void* const* d_in, const int* in_sizes, int n_in,
                              void* d_out, int out_size, void* d_ws, size_t ws_size,
                              hipStream_t stream) {
  const float* x  = (const float*)d_in[0];
  const float* Wq = (const float*)d_in[1];
  const float* bq = (const float*)d_in[2];
  const float* Wk = (const float*)d_in[3];
  const float* bk = (const float*)d_in[4];
  const float* Wv = (const float*)d_in[5];
  const float* bv = (const float*)d_in[6];
  const float* mw = (const float*)d_in[7];
  const float* Wp = (const float*)d_in[8];
  const float* bp = (const float*)d_in[9];
  float* out = (float*)d_out;

  char* ws = (char*)d_ws;
  size_t off = 0;
  auto alloc = [&](size_t elems) {
    unsigned short* pp = (unsigned short*)(ws + off);
    off += elems * 2; off = (off + 255) & ~(size_t)255;
    return pp;
  };
  unsigned short* xb   = alloc((size_t)M_ * B_ * N_ * C_);
  unsigned short* Wqt  = alloc((size_t)M_ * C_ * C_);
  unsigned short* Wkt  = alloc((size_t)M_ * C_ * C_);
  unsigned short* Wvt  = alloc((size_t)M_ * C_ * C_);
  unsigned short* Wpt  = alloc((size_t)C_ * C_);
  unsigned short* qb   = alloc((size_t)M_ * B_ * H_ * N_ * HD_);
  unsigned short* kb   = alloc((size_t)M_ * B_ * H_ * N_ * HD_);
  unsigned short* vtb  = alloc((size_t)M_ * B_ * H_ * HD_ * N_);
  unsigned short* att9 = alloc((size_t)9 * B_ * N_ * C_);
  unsigned short* fb   = alloc((size_t)B_ * N_ * C_);

  convert_x_kernel<<<6144, 256, 0, stream>>>(x, xb, (M_ * B_ * N_ * C_) / 4);
  transpose_w_kernel<<<dim3(8, 8, 10), 256, 0, stream>>>(Wq, Wk, Wv, Wp, Wqt, Wkt, Wvt, Wpt);
  gemm128_kernel<0><<<dim3(32, 4, 9), 256, 0, stream>>>(xb, Wqt, Wkt, Wvt, bq, bk, bv,
                                                        qb, kb, vtb, nullptr);
  attn_kernel<<<2304, 256, 0, stream>>>(qb, kb, vtb, mw, att9);
  sum9_kernel<<<1024, 256, 0, stream>>>(att9, fb, (B_ * N_ * C_) / 8);
  gemm128_kernel<1><<<dim3(32, 4, 1), 256, 0, stream>>>(fb, Wpt, nullptr, nullptr, bp, nullptr, nullptr,
                                                        nullptr, nullptr, nullptr, out);
}

// Round 9
// 195.936 us; speedup vs baseline: 1.1864x; 1.0319x over previous
//
#include <hip/hip_runtime.h>
#include <stdint.h>

#define M_ 3
#define B_ 8
#define N_ 512
#define C_ 512
#define H_ 8
#define HD_ 64

typedef __bf16 bf16x8 __attribute__((ext_vector_type(8)));
typedef __bf16 bf16x2 __attribute__((ext_vector_type(2)));
typedef float f32x4 __attribute__((ext_vector_type(4)));
typedef float f32x16 __attribute__((ext_vector_type(16)));
typedef unsigned int u32x4 __attribute__((ext_vector_type(4)));

#if __has_builtin(__builtin_amdgcn_exp2f)
#define EXP2(x) __builtin_amdgcn_exp2f(x)
#else
#define EXP2(x) __expf((x)*0.69314718056f)
#endif

// K is pre-scaled by hd^-0.5 * log2(e) in the K-projection epilogue,
// so attention probabilities are exp2(S) directly.
#define K_PRESCALE 0.18033688f

static __device__ __forceinline__ unsigned short f2bf(float f) {
  unsigned int u = __float_as_uint(f);
  unsigned int r = (u + 0x7FFFu + ((u >> 16) & 1u)) >> 16;
  return (unsigned short)r;
}
static __device__ __forceinline__ float bf2f(unsigned short s) {
  return __uint_as_float(((unsigned int)s) << 16);
}

static __device__ __forceinline__ void gll16(const void* g, void* l) {
  __builtin_amdgcn_global_load_lds(
      (const __attribute__((address_space(1))) unsigned int*)g,
      (__attribute__((address_space(3))) unsigned int*)l, 16, 0, 0);
}

// ---------------- kernel 1: prep = convert x (f32->bf16) + transpose weights ----
// blocks [0, 6144): x conversion; blocks [6144, 6784): W transpose-convert.
__global__ void prep_kernel(const float* __restrict__ x,
                            const float* __restrict__ Wq, const float* __restrict__ Wk,
                            const float* __restrict__ Wv, const float* __restrict__ Wp,
                            unsigned short* __restrict__ xb,
                            unsigned short* __restrict__ Wqt, unsigned short* __restrict__ Wkt,
                            unsigned short* __restrict__ Wvt, unsigned short* __restrict__ Wpt) {
  __shared__ unsigned short t[64][68];
  if (blockIdx.x < 6144) {
    int i = blockIdx.x * 256 + threadIdx.x;
    float4 v = ((const float4*)x)[i];
    ushort4 o;
    o.x = f2bf(v.x); o.y = f2bf(v.y); o.z = f2bf(v.z); o.w = f2bf(v.w);
    ((ushort4*)xb)[i] = o;
    return;
  }
  int tz = blockIdx.x - 6144;           // 0..639
  int z = tz >> 6, rem = tz & 63;
  const float* src; unsigned short* dst;
  if (z < 3)      { src = Wq + z * 262144;       dst = Wqt + z * 262144; }
  else if (z < 6) { src = Wk + (z - 3) * 262144; dst = Wkt + (z - 3) * 262144; }
  else if (z < 9) { src = Wv + (z - 6) * 262144; dst = Wvt + (z - 6) * 262144; }
  else            { src = Wp;                     dst = Wpt; }
  int r0 = (rem >> 3) * 64, c0 = (rem & 7) * 64;
  int tr = threadIdx.x >> 4, tc = (threadIdx.x & 15) * 4;
#pragma unroll
  for (int it = 0; it < 4; ++it) {
    int r = tr + it * 16;
    float4 v = *(const float4*)&src[(size_t)(r0 + r) * 512 + c0 + tc];
    t[tc + 0][r] = f2bf(v.x); t[tc + 1][r] = f2bf(v.y);
    t[tc + 2][r] = f2bf(v.z); t[tc + 3][r] = f2bf(v.w);
  }
  __syncthreads();
#pragma unroll
  for (int it = 0; it < 4; ++it) {
    int d = tr + it * 16;
    ushort4 o;
    o.x = t[d][tc + 0]; o.y = t[d][tc + 1]; o.z = t[d][tc + 2]; o.w = t[d][tc + 3];
    *(ushort4*)&dst[(size_t)(c0 + d) * 512 + r0 + tc] = o;
  }
}

// ---------------- kernel 2/5: 128x128 bf16 MFMA GEMM ----------------
template <int MODE>
__launch_bounds__(256, 2)
__global__ void gemm128_kernel(const unsigned short* __restrict__ Aall,
                               const unsigned short* __restrict__ Bt0,
                               const unsigned short* __restrict__ Bt1,
                               const unsigned short* __restrict__ Bt2,
                               const float* __restrict__ bias0,
                               const float* __restrict__ bias1,
                               const float* __restrict__ bias2,
                               unsigned short* __restrict__ outQ,
                               unsigned short* __restrict__ outK,
                               unsigned short* __restrict__ outVt,
                               float* __restrict__ outF) {
  const int tid = threadIdx.x;
  const int wv = tid >> 6, l = tid & 63;
  const int wr = wv >> 1, wc = wv & 1;
  const int bm = blockIdx.x, bn = blockIdx.y;
  int m = 0, p = 0;
  const unsigned short* A; const unsigned short* Bt; const float* bias;
  if (MODE == 0) {
    int z = blockIdx.z; m = z / 3; p = z % 3;
    A = Aall + (size_t)m * (B_ * N_ * C_);
    Bt = (p == 0 ? Bt0 : p == 1 ? Bt1 : Bt2) + (size_t)m * (C_ * C_);
    bias = (p == 0 ? bias0 : p == 1 ? bias1 : bias2) + m * C_;
  } else {
    A = Aall; Bt = Bt0; bias = bias0;
  }
  __shared__ __align__(16) unsigned short lA[2][128 * 64];
  __shared__ __align__(16) unsigned short lB[2][128 * 64];
  f32x4 acc[4][4] = {};

  auto stage = [&](int buf, int kt) {
    int k0 = kt * 64;
#pragma unroll
    for (int it = 0; it < 4; ++it) {
      int f = (it * 256 + tid) * 16;
      int r = f >> 7, o = f & 127;
      int so = o ^ ((r & 7) << 4);
      gll16((const char*)A + ((size_t)(bm * 128 + r) * 512 + k0) * 2 + so,
            (char*)&lA[buf][0] + (it * 256 + wv * 64) * 16);
      gll16((const char*)Bt + ((size_t)(bn * 128 + r) * 512 + k0) * 2 + so,
            (char*)&lB[buf][0] + (it * 256 + wv * 64) * 16);
    }
  };

  stage(0, 0);
  __syncthreads();
  int buf = 0;
  for (int kt = 0; kt < 8; ++kt) {
    if (kt < 7) stage(buf ^ 1, kt + 1);
    bf16x8 aF[4][2], bF[4][2];
#pragma unroll
    for (int rt = 0; rt < 4; ++rt)
#pragma unroll
      for (int kf = 0; kf < 2; ++kf) {
        int rowA = wr * 64 + rt * 16 + (l & 15);
        int rowB = wc * 64 + rt * 16 + (l & 15);
        int kb = kf * 64 + (l >> 4) * 16;
        aF[rt][kf] = *(const bf16x8*)((const char*)&lA[buf][0] + rowA * 128 + (kb ^ ((rowA & 7) << 4)));
        bF[rt][kf] = *(const bf16x8*)((const char*)&lB[buf][0] + rowB * 128 + (kb ^ ((rowB & 7) << 4)));
      }
#pragma unroll
    for (int kf = 0; kf < 2; ++kf)
#pragma unroll
      for (int rt = 0; rt < 4; ++rt)
#pragma unroll
        for (int ct = 0; ct < 4; ++ct)
          acc[rt][ct] = __builtin_amdgcn_mfma_f32_16x16x32_bf16(aF[rt][kf], bF[ct][kf], acc[rt][ct], 0, 0, 0);
    __syncthreads();
    buf ^= 1;
  }

  const float vscale = (MODE == 0 && p == 1) ? K_PRESCALE : 1.0f;
#pragma unroll
  for (int rt = 0; rt < 4; ++rt) {
    int rbase = bm * 128 + wr * 64 + rt * 16 + (l >> 4) * 4;
#pragma unroll
    for (int ct = 0; ct < 4; ++ct) {
      int col = bn * 128 + wc * 64 + ct * 16 + (l & 15);
      float bb = bias[col];
      if (MODE == 0) {
        int h = col >> 6, hd = col & 63;
        if (p < 2) {
          unsigned short* out = (p == 0 ? outQ : outK) + (size_t)m * (B_ * H_ * N_ * HD_);
#pragma unroll
          for (int jr = 0; jr < 4; ++jr) {
            int row = rbase + jr; int b = row >> 9, n = row & 511;
            out[(((size_t)(b * H_ + h) * N_ + n) * HD_) + hd] = f2bf((acc[rt][ct][jr] + bb) * vscale);
          }
        } else {
          unsigned short* out = outVt + (size_t)m * (B_ * H_ * HD_ * N_);
          int row = rbase; int b = row >> 9, n = row & 511;
          ushort4 o;
          o.x = f2bf(acc[rt][ct][0] + bb);
          o.y = f2bf(acc[rt][ct][1] + bb);
          o.z = f2bf(acc[rt][ct][2] + bb);
          o.w = f2bf(acc[rt][ct][3] + bb);
          *(ushort4*)&out[(((size_t)(b * H_ + h) * HD_ + hd) * N_) + n] = o;
        }
      } else {
#pragma unroll
        for (int jr = 0; jr < 4; ++jr) {
          int row = rbase + jr;
          outF[(size_t)row * C_ + col] = acc[rt][ct][jr] + bb;
        }
      }
    }
  }
}

// ---------------- kernel 3: pairwise attention v7 ----------------
// v4 structure, but K/V LDS tiles are 32 rows x 256B with slot-XOR over 16
// slots (s = s0 ^ (row&15)). Fragment reads alias only 2-way (free, m136);
// staging sources remain 8x128B contiguous per wave (v4-level coalescing).
__launch_bounds__(256, 4)
__global__ void attn_kernel(const unsigned short* __restrict__ qg,
                            const unsigned short* __restrict__ kg,
                            const unsigned short* __restrict__ vg,
                            const float* __restrict__ mw,
                            unsigned short* __restrict__ att9) {
  const int tid = threadIdx.x;
  const int wv = tid >> 6, l = tid & 63;
  const int hi = l >> 5, lq = l & 31;
  const int xcd = blockIdx.x & 7, slot = blockIdx.x >> 3;
  const int bh = (xcd << 3) | (slot & 7);   // blocks sharing (b,h) co-locate per XCD
  const int r_ = slot >> 3;                 // 0..35
  const int qt = r_ & 3, ij = r_ >> 2;      // ij = i*3+j, 0..8
  const int i = ij / 3, j = ij % 3;
  const int b = bh >> 3, h = bh & 7;
  const int n0 = qt * 128;

  __shared__ __align__(16) unsigned short lK[2][32 * 128];  // 32 rows x 256B
  __shared__ __align__(16) unsigned short lV[2][32 * 128];

  // Q B-frags: lane holds Q[q = n0+wv*32+lq][d = ks*16 + hi*8 + 0..7]
  bf16x8 qB[4];
  {
    const unsigned short* qb = qg + (size_t)((i * B_ + b) * H_ + h) * N_ * HD_;
    int n = n0 + wv * 32 + lq;
#pragma unroll
    for (int ks = 0; ks < 4; ++ks)
      qB[ks] = *(const bf16x8*)&qb[(size_t)n * HD_ + ks * 16 + hi * 8];
  }
  bf16x8 onesB;
#pragma unroll
  for (int zz = 0; zz < 8; ++zz) onesB[zz] = (__bf16)1.0f;

  const char* kb = (const char*)(kg + (size_t)((j * B_ + b) * H_ + h) * N_ * HD_);
  const char* vb = (const char*)(vg + (size_t)((j * B_ + b) * H_ + h) * HD_ * N_);
  // Staging: chunk c (16B) -> LDS row c>>4, slot c&15. Stored slot s holds
  // nominal slot s0 = s ^ (row&15); s0 = half*8 + d16 selects key/hd half
  // and 16B-offset. Per wave: 8 contiguous 128B global segments.
  auto stage = [&](int buf, int kt) {
#pragma unroll
    for (int it = 0; it < 2; ++it) {
      int c = it * 256 + tid;
      int row = c >> 4, s = c & 15;
      int s0 = s ^ (row & 15);
      int hh = s0 >> 3, d16 = s0 & 7;
      gll16(kb + (size_t)(kt * 64 + hh * 32 + row) * 128 + d16 * 16,
            (char*)&lK[buf][0] + (it * 256 + wv * 64) * 16);
      gll16(vb + (size_t)(hh * 32 + row) * 1024 + kt * 128 + d16 * 16,
            (char*)&lV[buf][0] + (it * 256 + wv * 64) * 16);
    }
  };
  stage(0, 0);
  __syncthreads();

  f32x16 oacc[2] = {};
  f32x16 dacc = {};
  int buf = 0;
  for (int kt = 0; kt < 8; ++kt) {
    if (kt < 7) stage(buf ^ 1, kt + 1);
#pragma unroll
    for (int kt2 = 0; kt2 < 2; ++kt2) {
      // S^T tile: rows = 32 keys, cols = 32 q (swapped operands).
      // kA: key = kt2*32+lq -> row lq, s0 = kt2*8 + ks*2 + hi.
      f32x16 sT = {};
#pragma unroll
      for (int ks = 0; ks < 4; ++ks) {
        int sK = (kt2 * 8 + ks * 2 + hi) ^ (lq & 15);
        bf16x8 kA = *(const bf16x8*)((const char*)&lK[buf][0] + lq * 256 + sK * 16);
        sT = __builtin_amdgcn_mfma_f32_32x32x16_bf16(kA, qB[ks], sT, 0, 0, 0);
      }
      // P = exp2(S) (K pre-scaled); pack pairs via compiler cvt_pk
      unsigned int c[8];
#pragma unroll
      for (int w = 0; w < 8; ++w) {
        bf16x2 t2;
        t2[0] = (__bf16)EXP2(sT[2 * w]);
        t2[1] = (__bf16)EXP2(sT[2 * w + 1]);
        c[w] = __builtin_bit_cast(unsigned int, t2);
      }
      // PV + denominator per 16-key slice
#pragma unroll
      for (int hs = 0; hs < 2; ++hs) {
        int ksg = kt2 * 2 + hs;
        unsigned int s0_ = hi ? c[4 * hs + 0] : c[4 * hs + 2];
        unsigned int s1_ = hi ? c[4 * hs + 1] : c[4 * hs + 3];
        unsigned int r0 = (unsigned int)__shfl_xor((int)s0_, 32, 64);
        unsigned int r1 = (unsigned int)__shfl_xor((int)s1_, 32, 64);
        u32x4 pw;
        pw.x = hi ? r0 : c[4 * hs + 0];
        pw.y = hi ? r1 : c[4 * hs + 1];
        pw.z = hi ? c[4 * hs + 2] : r0;
        pw.w = hi ? c[4 * hs + 3] : r1;
        bf16x8 pA = __builtin_bit_cast(bf16x8, pw);
        dacc = __builtin_amdgcn_mfma_f32_32x32x16_bf16(pA, onesB, dacc, 0, 0, 0);
#pragma unroll
        for (int ht = 0; ht < 2; ++ht) {
          // vB: hd = ht*32+lq -> row lq, s0 = ht*8 + ksg*2 + hi.
          int sV = (ht * 8 + ksg * 2 + hi) ^ (lq & 15);
          bf16x8 vB = *(const bf16x8*)((const char*)&lV[buf][0] + lq * 256 + sV * 16);
          oacc[ht] = __builtin_amdgcn_mfma_f32_32x32x16_bf16(pA, vB, oacc[ht], 0, 0, 0);
        }
      }
    }
    __syncthreads();
    buf ^= 1;
  }

  // finish: weight / denominator (lane-local: dacc has same C/D layout), write
  float w = mw[ij] * (1.0f / 3.0f);
  unsigned short* outp = att9 + (size_t)ij * (B_ * N_ * C_);
#pragma unroll
  for (int reg = 0; reg < 16; ++reg) {
    float t = w / dacc[reg];
    int n = n0 + wv * 32 + (reg & 3) + 8 * (reg >> 2) + 4 * hi;
#pragma unroll
    for (int ht = 0; ht < 2; ++ht) {
      int cc = h * 64 + ht * 32 + lq;
      outp[((size_t)b * N_ + n) * C_ + cc] = f2bf(oacc[ht][reg] * t);
    }
  }
}

// ---------------- kernel 4: sum 9 weighted partials -> fused bf16 ----------------
__global__ void sum9_kernel(const unsigned short* __restrict__ att9,
                            unsigned short* __restrict__ o, int n8) {
  int idx = blockIdx.x * 256 + threadIdx.x;
  if (idx >= n8) return;
  float acc[8] = {};
#pragma unroll
  for (int s = 0; s < 9; ++s) {
    uint4 v = ((const uint4*)(att9 + (size_t)s * (B_ * N_ * C_)))[idx];
    acc[0] += bf2f((unsigned short)(v.x & 0xffff));
    acc[1] += bf2f((unsigned short)(v.x >> 16));
    acc[2] += bf2f((unsigned short)(v.y & 0xffff));
    acc[3] += bf2f((unsigned short)(v.y >> 16));
    acc[4] += bf2f((unsigned short)(v.z & 0xffff));
    acc[5] += bf2f((unsigned short)(v.z >> 16));
    acc[6] += bf2f((unsigned short)(v.w & 0xffff));
    acc[7] += bf2f((unsigned short)(v.w >> 16));
  }
  uint4 r;
  r.x = (unsigned int)f2bf(acc[0]) | ((unsigned int)f2bf(acc[1]) << 16);
  r.y = (unsigned int)f2bf(acc[2]) | ((unsigned int)f2bf(acc[3]) << 16);
  r.z = (unsigned int)f2bf(acc[4]) | ((unsigned int)f2bf(acc[5]) << 16);
  r.w = (unsigned int)f2bf(acc[6]) | ((unsigned int)f2bf(acc[7]) << 16);
  ((uint4*)o)[idx] = r;
}

extern "C" void kernel_launch(void* const* d_in, const int* in_sizes, int n_in,
                              void* d_out, int out_size, void* d_ws, size_t ws_size,
                              hipStream_t stream) {
  const float* x  = (const float*)d_in[0];
  const float* Wq = (const float*)d_in[1];
  const float* bq = (const float*)d_in[2];
  const float* Wk = (const float*)d_in[3];
  const float* bk = (const float*)d_in[4];
  const float* Wv = (const float*)d_in[5];
  const float* bv = (const float*)d_in[6];
  const float* mw = (const float*)d_in[7];
  const float* Wp = (const float*)d_in[8];
  const float* bp = (const float*)d_in[9];
  float* out = (float*)d_out;

  char* ws = (char*)d_ws;
  size_t off = 0;
  auto alloc = [&](size_t elems) {
    unsigned short* pp = (unsigned short*)(ws + off);
    off += elems * 2; off = (off + 255) & ~(size_t)255;
    return pp;
  };
  unsigned short* xb   = alloc((size_t)M_ * B_ * N_ * C_);
  unsigned short* Wqt  = alloc((size_t)M_ * C_ * C_);
  unsigned short* Wkt  = alloc((size_t)M_ * C_ * C_);
  unsigned short* Wvt  = alloc((size_t)M_ * C_ * C_);
  unsigned short* Wpt  = alloc((size_t)C_ * C_);
  unsigned short* qb   = alloc((size_t)M_ * B_ * H_ * N_ * HD_);
  unsigned short* kb   = alloc((size_t)M_ * B_ * H_ * N_ * HD_);
  unsigned short* vtb  = alloc((size_t)M_ * B_ * H_ * HD_ * N_);
  unsigned short* att9 = alloc((size_t)9 * B_ * N_ * C_);
  unsigned short* fb   = alloc((size_t)B_ * N_ * C_);

  prep_kernel<<<6784, 256, 0, stream>>>(x, Wq, Wk, Wv, Wp, xb, Wqt, Wkt, Wvt, Wpt);
  gemm128_kernel<0><<<dim3(32, 4, 9), 256, 0, stream>>>(xb, Wqt, Wkt, Wvt, bq, bk, bv,
                                                        qb, kb, vtb, nullptr);
  attn_kernel<<<2304, 256, 0, stream>>>(qb, kb, vtb, mw, att9);
  sum9_kernel<<<1024, 256, 0, stream>>>(att9, fb, (B_ * N_ * C_) / 8);
  gemm128_kernel<1><<<dim3(32, 4, 1), 256, 0, stream>>>(fb, Wpt, nullptr, nullptr, bp, nullptr, nullptr,
                                                        nullptr, nullptr, nullptr, out);
}